// Round 4
// baseline (1400.575 us; speedup 1.0000x reference)
//
#include <hip/hip_runtime.h>
#include <hip/hip_bf16.h>
#include <hip/hip_fp16.h>
#include <stdint.h>

#define CH 128
#define NCHUNK 512          // edge chunks for counting sort
#define MAXBKT 2048         // >= ceil(N/64)

static __device__ __forceinline__ float4 ld4(const float* p) {
    return *reinterpret_cast<const float4*>(p);
}
static __device__ __forceinline__ float f4get(const float4& v, int i) {
    return i == 0 ? v.x : i == 1 ? v.y : i == 2 ? v.z : v.w;  // i constant after unroll
}

// ---------------- phase 1: per-chunk bucket histograms (LDS atomics only) ----------
__global__ void k_bhist(const int* __restrict__ dst, int* __restrict__ H,
                        int nE, int nbkt, int chunkSz) {
    __shared__ int hist[MAXBKT];
    int c = blockIdx.x, tid = threadIdx.x;
    for (int i = tid; i < nbkt; i += 256) hist[i] = 0;
    __syncthreads();
    int s = c * chunkSz, e = min(s + chunkSz, nE);
    for (int i = s + tid; i < e; i += 256) atomicAdd(&hist[dst[i] >> 6], 1);
    __syncthreads();
    for (int i = tid; i < nbkt; i += 256) H[c * nbkt + i] = hist[i];
}

// ---------------- phase 2a: per-bucket totals (column sums of H) ----------
__global__ void k_btot(const int* __restrict__ H, int* __restrict__ T, int nchunk, int nbkt) {
    __shared__ int sd[256];
    int b = blockIdx.x, tid = threadIdx.x;
    int v = 0;
    for (int c = tid; c < nchunk; c += 256) v += H[c * nbkt + b];
    sd[tid] = v;
    __syncthreads();
    for (int o = 128; o > 0; o >>= 1) {
        if (tid < o) sd[tid] += sd[tid + o];
        __syncthreads();
    }
    if (tid == 0) T[b] = sd[0];
}

// ---------------- phase 2b: exclusive scan of bucket totals -> base ----------
__global__ __launch_bounds__(1024) void k_bscan(const int* __restrict__ T,
                                                int* __restrict__ base, int nbkt) {
    __shared__ int ps[1024];
    int t = threadIdx.x;
    int a0 = (2 * t < nbkt) ? T[2 * t] : 0;
    int a1 = (2 * t + 1 < nbkt) ? T[2 * t + 1] : 0;
    ps[t] = a0 + a1;
    __syncthreads();
    for (int d = 1; d < 1024; d <<= 1) {
        int v = (t >= d) ? ps[t - d] : 0;
        __syncthreads();
        ps[t] += v;
        __syncthreads();
    }
    int excl = t ? ps[t - 1] : 0;   // exclusive pair prefix
    if (2 * t < nbkt) base[2 * t] = excl;
    if (2 * t + 1 < nbkt) base[2 * t + 1] = excl + a0;
    if (t == 0) base[nbkt] = ps[1023];
}

// ---------------- phase 2c: per-(chunk,bucket) offsets, in place over H ----------
__global__ __launch_bounds__(512) void k_boff(int* H, const int* __restrict__ base,
                                              int nchunk, int nbkt) {
    __shared__ int sd[NCHUNK];
    int b = blockIdx.x, t = threadIdx.x;
    int v = (t < nchunk) ? H[t * nbkt + b] : 0;
    sd[t] = v;
    __syncthreads();
    for (int d = 1; d < NCHUNK; d <<= 1) {
        int tv = (t >= d) ? sd[t - d] : 0;
        __syncthreads();
        sd[t] += tv;
        __syncthreads();
    }
    if (t < nchunk) H[t * nbkt + b] = base[b] + sd[t] - v;   // exclusive within bucket
}

// ---------------- phase 3: scatter (LDS cursors, plain global stores) ----------
// sorted[pos] = src | (dst&63)<<17  (src < 2^17 since N=100000)
__global__ void k_bscatter(const int* __restrict__ src, const int* __restrict__ dst,
                           const int* __restrict__ H, int* __restrict__ sorted,
                           int nE, int nbkt, int chunkSz) {
    __shared__ int cur[MAXBKT];
    int c = blockIdx.x, tid = threadIdx.x;
    for (int i = tid; i < nbkt; i += 256) cur[i] = H[c * nbkt + i];
    __syncthreads();
    int s = c * chunkSz, e = min(s + chunkSz, nE);
    for (int i = s + tid; i < e; i += 256) {
        int d = dst[i];
        int pos = atomicAdd(&cur[d >> 6], 1);
        sorted[pos] = src[i] | ((d & 63) << 17);
    }
}

// ---------------- x -> fp16 copy (halves gather bytes) ----------------
__global__ void k_tofp16(const float* __restrict__ x, uint32_t* __restrict__ xh, int n8) {
    int i = blockIdx.x * blockDim.x + threadIdx.x;
    int st = gridDim.x * blockDim.x;
    for (; i < n8; i += st) {
        float4 v0 = ld4(x + (size_t)i * 8);
        float4 v1 = ld4(x + (size_t)i * 8 + 4);
        __half2 h0 = __floats2half2_rn(v0.x, v0.y);
        __half2 h1 = __floats2half2_rn(v0.z, v0.w);
        __half2 h2 = __floats2half2_rn(v1.x, v1.y);
        __half2 h3 = __floats2half2_rn(v1.z, v1.w);
        uint4 o;
        o.x = *reinterpret_cast<unsigned*>(&h0);
        o.y = *reinterpret_cast<unsigned*>(&h1);
        o.z = *reinterpret_cast<unsigned*>(&h2);
        o.w = *reinterpret_cast<unsigned*>(&h3);
        reinterpret_cast<uint4*>(xh)[i] = o;
    }
}

// ---------------- fused bucket aggregate: h[node] = x[node] + sum_edges xh[src] ----
// One block per 64-node bucket; 32KB LDS accumulator; ds_add_f32 for cross-wave sums.
__global__ __launch_bounds__(256, 4) void k_baccum(const float* __restrict__ x,
        const __half2* __restrict__ xh, const float* __restrict__ xf,
        const int* __restrict__ sorted, const int* __restrict__ base,
        float* __restrict__ h, int n, int nbkt) {
    __shared__ float acc[64 * CH];   // 32 KiB
    int b = blockIdx.x;
    if (b >= nbkt) return;
    int tid = threadIdx.x;
    int node0 = b * 64;

    // init accumulator with x rows (zero for out-of-range tail nodes)
    for (int i = tid; i < 64 * CH / 4; i += 256) {
        int row = i >> 5;
        int node = node0 + row;
        float4 v = (node < n) ? ld4(&x[(size_t)node * CH + (i & 31) * 4])
                              : make_float4(0.f, 0.f, 0.f, 0.f);
        *reinterpret_cast<float4*>(&acc[i * 4]) = v;
    }
    __syncthreads();

    int s = base[b], e = base[b + 1];
    int wv = tid >> 6, lane = tid & 63;
    if (xh) {
        for (int i = s + wv * 2; i < e; i += 8) {
            int p0 = sorted[i];
            int s0 = p0 & 0x1FFFF, l0 = (p0 >> 17) & 63;
            float2 v0 = __half22float2(xh[(size_t)s0 * 64 + lane]);
            if (i + 1 < e) {
                int p1 = sorted[i + 1];
                int s1 = p1 & 0x1FFFF, l1 = (p1 >> 17) & 63;
                float2 v1 = __half22float2(xh[(size_t)s1 * 64 + lane]);
                atomicAdd(&acc[l0 * CH + lane * 2], v0.x);
                atomicAdd(&acc[l0 * CH + lane * 2 + 1], v0.y);
                atomicAdd(&acc[l1 * CH + lane * 2], v1.x);
                atomicAdd(&acc[l1 * CH + lane * 2 + 1], v1.y);
            } else {
                atomicAdd(&acc[l0 * CH + lane * 2], v0.x);
                atomicAdd(&acc[l0 * CH + lane * 2 + 1], v0.y);
            }
        }
    } else {
        for (int i = s + wv * 2; i < e; i += 8) {
            int p0 = sorted[i];
            int s0 = p0 & 0x1FFFF, l0 = (p0 >> 17) & 63;
            float2 v0 = *reinterpret_cast<const float2*>(&xf[(size_t)s0 * CH + lane * 2]);
            if (i + 1 < e) {
                int p1 = sorted[i + 1];
                int s1 = p1 & 0x1FFFF, l1 = (p1 >> 17) & 63;
                float2 v1 = *reinterpret_cast<const float2*>(&xf[(size_t)s1 * CH + lane * 2]);
                atomicAdd(&acc[l0 * CH + lane * 2], v0.x);
                atomicAdd(&acc[l0 * CH + lane * 2 + 1], v0.y);
                atomicAdd(&acc[l1 * CH + lane * 2], v1.x);
                atomicAdd(&acc[l1 * CH + lane * 2 + 1], v1.y);
            } else {
                atomicAdd(&acc[l0 * CH + lane * 2], v0.x);
                atomicAdd(&acc[l0 * CH + lane * 2 + 1], v0.y);
            }
        }
    }
    __syncthreads();

    for (int i = tid; i < 64 * CH / 4; i += 256) {
        int row = i >> 5;
        int node = node0 + row;
        if (node < n)
            *reinterpret_cast<float4*>(&h[(size_t)node * CH + (i & 31) * 4]) =
                *reinterpret_cast<float4*>(&acc[i * 4]);
    }
}

// ---------------- 128-K GEMM + bias; optional BN-on-load, relu, BN-stat partials ----
__global__ __launch_bounds__(256, 2) void k_gemm128(const float* A, const float* __restrict__ W,
        const float* __restrict__ bias, float* C, float* __restrict__ stats,
        const float* __restrict__ bnsc,   // if nonnull: a = relu(a*sc[k] + sh[k]) on load
        int nrows, int doStats, int doRelu) {
    __shared__ float Wl[CH * CH];   // 64 KiB
    int tid = threadIdx.x;
    for (int i = tid; i < CH * CH / 4; i += 256)
        reinterpret_cast<float4*>(Wl)[i] = reinterpret_cast<const float4*>(W)[i];
    __syncthreads();

    int cg = tid & 15;
    int rg = tid >> 4;
    float b8[8];
#pragma unroll
    for (int j = 0; j < 8; ++j) b8[j] = bias[cg * 8 + j];
    float ssum[8], ssq[8];
#pragma unroll
    for (int j = 0; j < 8; ++j) { ssum[j] = 0.f; ssq[j] = 0.f; }

    int nchunks = (nrows + 127) >> 7;
    for (int chunk = blockIdx.x; chunk < nchunks; chunk += gridDim.x) {
        int row0 = chunk * 128 + rg * 8;
        const float* Ap[8];
#pragma unroll
        for (int r = 0; r < 8; ++r)
            Ap[r] = A + (size_t)min(row0 + r, nrows - 1) * CH;

        float acc[8][8];
#pragma unroll
        for (int r = 0; r < 8; ++r)
#pragma unroll
            for (int j = 0; j < 8; ++j) acc[r][j] = 0.f;

        for (int k = 0; k < CH; k += 4) {
            float4 a[8];
#pragma unroll
            for (int r = 0; r < 8; ++r) a[r] = ld4(Ap[r] + k);
            if (bnsc) {
                float4 sc = ld4(bnsc + k), sh = ld4(bnsc + CH + k);
#pragma unroll
                for (int r = 0; r < 8; ++r) {
                    a[r].x = fmaxf(fmaf(a[r].x, sc.x, sh.x), 0.f);
                    a[r].y = fmaxf(fmaf(a[r].y, sc.y, sh.y), 0.f);
                    a[r].z = fmaxf(fmaf(a[r].z, sc.z, sh.z), 0.f);
                    a[r].w = fmaxf(fmaf(a[r].w, sc.w, sh.w), 0.f);
                }
            }
#pragma unroll
            for (int kk = 0; kk < 4; ++kk) {
                float4 w0 = ld4(&Wl[(k + kk) * CH + cg * 8]);
                float4 w1 = ld4(&Wl[(k + kk) * CH + cg * 8 + 4]);
#pragma unroll
                for (int r = 0; r < 8; ++r) {
                    float e = f4get(a[r], kk);
                    acc[r][0] += e * w0.x; acc[r][1] += e * w0.y;
                    acc[r][2] += e * w0.z; acc[r][3] += e * w0.w;
                    acc[r][4] += e * w1.x; acc[r][5] += e * w1.y;
                    acc[r][6] += e * w1.z; acc[r][7] += e * w1.w;
                }
            }
        }

        __syncthreads();   // in-place safety
#pragma unroll
        for (int r = 0; r < 8; ++r) {
            int row = row0 + r;
            if (row < nrows) {
                float v[8];
#pragma unroll
                for (int j = 0; j < 8; ++j) {
                    float t = acc[r][j] + b8[j];
                    if (doRelu) t = fmaxf(t, 0.f);
                    v[j] = t;
                }
                if (doStats) {
#pragma unroll
                    for (int j = 0; j < 8; ++j) { ssum[j] += v[j]; ssq[j] += v[j] * v[j]; }
                }
                *reinterpret_cast<float4*>(&C[(size_t)row * CH + cg * 8]) =
                    make_float4(v[0], v[1], v[2], v[3]);
                *reinterpret_cast<float4*>(&C[(size_t)row * CH + cg * 8 + 4]) =
                    make_float4(v[4], v[5], v[6], v[7]);
            }
        }
    }

    if (doStats) {
#pragma unroll
        for (int j = 0; j < 8; ++j) {
            ssum[j] += __shfl_xor(ssum[j], 16, 64); ssum[j] += __shfl_xor(ssum[j], 32, 64);
            ssq[j]  += __shfl_xor(ssq[j], 16, 64);  ssq[j]  += __shfl_xor(ssq[j], 32, 64);
        }
        __syncthreads();
        float* red = Wl;
        int wv = tid >> 6, lane = tid & 63;
        if (lane < 16) {
#pragma unroll
            for (int j = 0; j < 8; ++j) {
                red[wv * 128 + lane * 8 + j] = ssum[j];
                red[512 + wv * 128 + lane * 8 + j] = ssq[j];
            }
        }
        __syncthreads();
        if (tid < 128) {
            float s = 0.f, q = 0.f;
#pragma unroll
            for (int w = 0; w < 4; ++w) { s += red[w * 128 + tid]; q += red[512 + w * 128 + tid]; }
            atomicAdd(&stats[tid], s);
            atomicAdd(&stats[128 + tid], q);
        }
    }
}

// ---------------- BN finalize ----------------
__global__ void k_bnfin(const float* __restrict__ stats, const float* __restrict__ gamma,
        const float* __restrict__ beta, float* __restrict__ scsh, float invN) {
    int c = threadIdx.x;
    if (c < CH) {
        float mean = stats[c] * invN;
        float var = stats[CH + c] * invN - mean * mean;   // biased, as in ref
        float sc = gamma[c] * rsqrtf(var + 1e-5f);
        scsh[c] = sc;
        scsh[CH + c] = beta[c] - mean * sc;
    }
}

extern "C" void kernel_launch(void* const* d_in, const int* in_sizes, int n_in,
                              void* d_out, int out_size, void* d_ws, size_t ws_size,
                              hipStream_t stream) {
    const float* x     = (const float*)d_in[0];
    const int*   ei    = (const int*)d_in[1];
    const float* W1    = (const float*)d_in[2];
    const float* b1    = (const float*)d_in[3];
    const float* gamma = (const float*)d_in[4];
    const float* beta  = (const float*)d_in[5];
    const float* W2    = (const float*)d_in[6];
    const float* b2    = (const float*)d_in[7];
    float* out = (float*)d_out;

    const int N = in_sizes[0] / CH;   // 100000
    const int E = in_sizes[1] / 2;    // 1600000
    const int* esrc = ei;
    const int* edst = ei + E;
    const int nbkt = (N + 63) >> 6;   // 1563
    const int chunkSz = (E + NCHUNK - 1) / NCHUNK;

    char* w = (char*)d_ws;
    auto take = [&](size_t bytes) {
        char* p = w;
        w += (bytes + 255) & ~(size_t)255;
        return p;
    };
    int*      sorted = (int*)take((size_t)E * 4);
    int*      T      = (int*)take((size_t)(nbkt + 1) * 4);
    int*      base   = (int*)take((size_t)(nbkt + 1) * 4);
    float*    stats  = (float*)take(256 * 4);
    float*    scsh   = (float*)take(256 * 4);
    uint32_t* xh     = (uint32_t*)take((size_t)N * CH * 2);   // fp16 copy of x
    bool useFp16 = ((size_t)(w - (char*)d_ws) <= ws_size);

    // H[NCHUNK][nbkt] lives in d_out (dead until k_baccum overwrites all of d_out)
    int* H = (int*)d_out;
    float* h = out;   // d_out is the [N][128] fp32 intermediate after k_baccum

    hipMemsetAsync(stats, 0, 256 * 4, stream);

    k_bhist<<<NCHUNK, 256, 0, stream>>>(edst, H, E, nbkt, chunkSz);
    k_btot<<<nbkt, 256, 0, stream>>>(H, T, NCHUNK, nbkt);
    k_bscan<<<1, 1024, 0, stream>>>(T, base, nbkt);
    k_boff<<<nbkt, NCHUNK, 0, stream>>>(H, base, NCHUNK, nbkt);
    k_bscatter<<<NCHUNK, 256, 0, stream>>>(esrc, edst, H, sorted, E, nbkt, chunkSz);
    if (useFp16)
        k_tofp16<<<2048, 256, 0, stream>>>(x, xh, N * CH / 8);
    k_baccum<<<nbkt, 256, 0, stream>>>(x, useFp16 ? (const __half2*)xh : nullptr, x,
                                       sorted, base, h, N, nbkt);
    k_gemm128<<<512, 256, 0, stream>>>(h, W1, b1, h, stats, nullptr, N, 1, 0);
    k_bnfin<<<1, 128, 0, stream>>>(stats, gamma, beta, scsh, 1.0f / (float)N);
    k_gemm128<<<512, 256, 0, stream>>>(h, W2, b2, out, nullptr, scsh, N, 0, 1);
}

// Round 5
// 309.796 us; speedup vs baseline: 4.5210x; 4.5210x over previous
//
#include <hip/hip_runtime.h>
#include <hip/hip_bf16.h>
#include <hip/hip_fp16.h>
#include <stdint.h>

#define CH 128
#define NCHUNK 512          // edge chunks for counting sort
#define MAXBKT 2048         // >= ceil(N/64)

static __device__ __forceinline__ float4 ld4(const float* p) {
    return *reinterpret_cast<const float4*>(p);
}
static __device__ __forceinline__ float f4get(const float4& v, int i) {
    return i == 0 ? v.x : i == 1 ? v.y : i == 2 ? v.z : v.w;  // i constant after unroll
}

// ---------------- phase 1: per-chunk bucket histograms (LDS atomics only) ----------
__global__ void k_bhist(const int* __restrict__ dst, int* __restrict__ H,
                        int nE, int nbkt, int chunkSz) {
    __shared__ int hist[MAXBKT];
    int c = blockIdx.x, tid = threadIdx.x;
    for (int i = tid; i < nbkt; i += 256) hist[i] = 0;
    __syncthreads();
    int s = c * chunkSz, e = min(s + chunkSz, nE);
    for (int i = s + tid; i < e; i += 256) atomicAdd(&hist[dst[i] >> 6], 1);
    __syncthreads();
    for (int i = tid; i < nbkt; i += 256) H[c * nbkt + i] = hist[i];
}

// ---------------- phase 2a: per-bucket totals (column sums of H) ----------
__global__ void k_btot(const int* __restrict__ H, int* __restrict__ T, int nchunk, int nbkt) {
    __shared__ int sd[256];
    int b = blockIdx.x, tid = threadIdx.x;
    int v = 0;
    for (int c = tid; c < nchunk; c += 256) v += H[c * nbkt + b];
    sd[tid] = v;
    __syncthreads();
    for (int o = 128; o > 0; o >>= 1) {
        if (tid < o) sd[tid] += sd[tid + o];
        __syncthreads();
    }
    if (tid == 0) T[b] = sd[0];
}

// ---------------- phase 2b: exclusive scan of bucket totals -> base ----------
__global__ __launch_bounds__(1024) void k_bscan(const int* __restrict__ T,
                                                int* __restrict__ base, int nbkt) {
    __shared__ int ps[1024];
    int t = threadIdx.x;
    int a0 = (2 * t < nbkt) ? T[2 * t] : 0;
    int a1 = (2 * t + 1 < nbkt) ? T[2 * t + 1] : 0;
    ps[t] = a0 + a1;
    __syncthreads();
    for (int d = 1; d < 1024; d <<= 1) {
        int v = (t >= d) ? ps[t - d] : 0;
        __syncthreads();
        ps[t] += v;
        __syncthreads();
    }
    int excl = t ? ps[t - 1] : 0;   // exclusive pair prefix
    if (2 * t < nbkt) base[2 * t] = excl;
    if (2 * t + 1 < nbkt) base[2 * t + 1] = excl + a0;
    if (t == 0) base[nbkt] = ps[1023];
}

// ---------------- phase 2c: per-(chunk,bucket) offsets, in place over H ----------
__global__ __launch_bounds__(512) void k_boff(int* H, const int* __restrict__ base,
                                              int nchunk, int nbkt) {
    __shared__ int sd[NCHUNK];
    int b = blockIdx.x, t = threadIdx.x;
    int v = (t < nchunk) ? H[t * nbkt + b] : 0;
    sd[t] = v;
    __syncthreads();
    for (int d = 1; d < NCHUNK; d <<= 1) {
        int tv = (t >= d) ? sd[t - d] : 0;
        __syncthreads();
        sd[t] += tv;
        __syncthreads();
    }
    if (t < nchunk) H[t * nbkt + b] = base[b] + sd[t] - v;   // exclusive within bucket
}

// ---------------- phase 3: bucket scatter (LDS cursors, plain global stores) ------
// sorted[pos] = src | (dst&63)<<17  (src < 2^17 since N=100000)
__global__ void k_bscatter(const int* __restrict__ src, const int* __restrict__ dst,
                           const int* __restrict__ H, int* __restrict__ sorted,
                           int nE, int nbkt, int chunkSz) {
    __shared__ int cur[MAXBKT];
    int c = blockIdx.x, tid = threadIdx.x;
    for (int i = tid; i < nbkt; i += 256) cur[i] = H[c * nbkt + i];
    __syncthreads();
    int s = c * chunkSz, e = min(s + chunkSz, nE);
    for (int i = s + tid; i < e; i += 256) {
        int d = dst[i];
        int pos = atomicAdd(&cur[d >> 6], 1);
        sorted[pos] = src[i] | ((d & 63) << 17);
    }
}

// ---------------- phase 4: within-bucket sort -> per-node CSR + offs ----------
// One block per bucket: 64-counter LDS histogram, wave-scan, plain stores to csr.
__global__ __launch_bounds__(256) void k_bsort2(const int* __restrict__ sorted,
        const int* __restrict__ base, int* __restrict__ csr, int* __restrict__ offs,
        int n, int nbkt, int nE) {
    __shared__ int hist[64];
    __shared__ int cur[64];
    int b = blockIdx.x, tid = threadIdx.x;
    if (tid < 64) hist[tid] = 0;
    __syncthreads();
    int s = base[b], e = base[b + 1];
    for (int i = s + tid; i < e; i += 256)
        atomicAdd(&hist[(sorted[i] >> 17) & 63], 1);
    __syncthreads();
    if (tid < 64) {
        int h0 = hist[tid];
        int v = h0;
        for (int d = 1; d < 64; d <<= 1) {      // inclusive wave scan
            int t = __shfl_up(v, d, 64);
            if (tid >= d) v += t;
        }
        int excl = base[b] + v - h0;
        int node = b * 64 + tid;
        if (node < n) offs[node] = excl;
        cur[tid] = excl;
    }
    if (b == 0 && tid == 0) offs[n] = nE;
    __syncthreads();
    for (int i = s + tid; i < e; i += 256) {
        int p = sorted[i];
        int pos = atomicAdd(&cur[(p >> 17) & 63], 1);
        csr[pos] = p & 0x1FFFF;
    }
}

// ---------------- x -> fp16 copy (halves gather bytes) ----------------
__global__ void k_tofp16(const float* __restrict__ x, uint32_t* __restrict__ xh, int n8) {
    int i = blockIdx.x * blockDim.x + threadIdx.x;
    int st = gridDim.x * blockDim.x;
    for (; i < n8; i += st) {
        float4 v0 = ld4(x + (size_t)i * 8);
        float4 v1 = ld4(x + (size_t)i * 8 + 4);
        __half2 h0 = __floats2half2_rn(v0.x, v0.y);
        __half2 h1 = __floats2half2_rn(v0.z, v0.w);
        __half2 h2 = __floats2half2_rn(v1.x, v1.y);
        __half2 h3 = __floats2half2_rn(v1.z, v1.w);
        uint4 o;
        o.x = *reinterpret_cast<unsigned*>(&h0);
        o.y = *reinterpret_cast<unsigned*>(&h1);
        o.z = *reinterpret_cast<unsigned*>(&h2);
        o.w = *reinterpret_cast<unsigned*>(&h3);
        reinterpret_cast<uint4*>(xh)[i] = o;
    }
}

// ---------------- GIN aggregate via fp16 gather: h[i] = x[i] + sum_j xh[src_j] ----
// One wave per node, register accumulation, 4 gathers in flight.
__global__ void k_aggregate_h(const float* __restrict__ x, const __half2* __restrict__ xh,
        const int* __restrict__ csr, const int* __restrict__ offs, float* __restrict__ h, int n) {
    int wid = (blockIdx.x * blockDim.x + threadIdx.x) >> 6;
    int lane = threadIdx.x & 63;
    int nw = (gridDim.x * blockDim.x) >> 6;
    for (int node = wid; node < n; node += nw) {
        float2 a0 = *reinterpret_cast<const float2*>(&x[(size_t)node * CH + lane * 2]);
        float2 a1 = make_float2(0.f, 0.f), a2 = make_float2(0.f, 0.f), a3 = make_float2(0.f, 0.f);
        int s = offs[node], e = offs[node + 1];
        int i = s;
        for (; i + 3 < e; i += 4) {
            int s0 = csr[i], s1 = csr[i + 1], s2 = csr[i + 2], s3 = csr[i + 3];
            float2 v0 = __half22float2(xh[(size_t)s0 * 64 + lane]);
            float2 v1 = __half22float2(xh[(size_t)s1 * 64 + lane]);
            float2 v2 = __half22float2(xh[(size_t)s2 * 64 + lane]);
            float2 v3 = __half22float2(xh[(size_t)s3 * 64 + lane]);
            a0.x += v0.x; a0.y += v0.y;
            a1.x += v1.x; a1.y += v1.y;
            a2.x += v2.x; a2.y += v2.y;
            a3.x += v3.x; a3.y += v3.y;
        }
        for (; i < e; ++i) {
            float2 v0 = __half22float2(xh[(size_t)csr[i] * 64 + lane]);
            a0.x += v0.x; a0.y += v0.y;
        }
        a0.x += a1.x + a2.x + a3.x;
        a0.y += a1.y + a2.y + a3.y;
        *reinterpret_cast<float2*>(&h[(size_t)node * CH + lane * 2]) = a0;
    }
}

// ---------------- fp32 fallback aggregate (if ws too small for fp16 copy) ----------
__global__ void k_aggregate(const float* __restrict__ x, const int* __restrict__ csr,
        const int* __restrict__ offs, float* __restrict__ h, int n) {
    int wid = (blockIdx.x * blockDim.x + threadIdx.x) >> 6;
    int lane = threadIdx.x & 63;
    int nw = (gridDim.x * blockDim.x) >> 6;
    int c = lane * 2;
    for (int node = wid; node < n; node += nw) {
        float2 a0 = *reinterpret_cast<const float2*>(&x[(size_t)node * CH + c]);
        float2 a1 = make_float2(0.f, 0.f);
        int s = offs[node], e = offs[node + 1];
        int i = s;
        for (; i + 1 < e; i += 2) {
            int s0 = csr[i], s1 = csr[i + 1];
            float2 v0 = *reinterpret_cast<const float2*>(&x[(size_t)s0 * CH + c]);
            float2 v1 = *reinterpret_cast<const float2*>(&x[(size_t)s1 * CH + c]);
            a0.x += v0.x; a0.y += v0.y;
            a1.x += v1.x; a1.y += v1.y;
        }
        if (i < e) {
            float2 v0 = *reinterpret_cast<const float2*>(&x[(size_t)csr[i] * CH + c]);
            a0.x += v0.x; a0.y += v0.y;
        }
        a0.x += a1.x; a0.y += a1.y;
        *reinterpret_cast<float2*>(&h[(size_t)node * CH + c]) = a0;
    }
}

// ---------------- 128-K GEMM + bias; optional BN-on-load, relu, BN-stat partials ----
__global__ __launch_bounds__(256, 2) void k_gemm128(const float* A, const float* __restrict__ W,
        const float* __restrict__ bias, float* C, float* __restrict__ stats,
        const float* __restrict__ bnsc,   // if nonnull: a = relu(a*sc[k] + sh[k]) on load
        int nrows, int doStats, int doRelu) {
    __shared__ float Wl[CH * CH];   // 64 KiB
    int tid = threadIdx.x;
    for (int i = tid; i < CH * CH / 4; i += 256)
        reinterpret_cast<float4*>(Wl)[i] = reinterpret_cast<const float4*>(W)[i];
    __syncthreads();

    int cg = tid & 15;
    int rg = tid >> 4;
    float b8[8];
#pragma unroll
    for (int j = 0; j < 8; ++j) b8[j] = bias[cg * 8 + j];
    float ssum[8], ssq[8];
#pragma unroll
    for (int j = 0; j < 8; ++j) { ssum[j] = 0.f; ssq[j] = 0.f; }

    int nchunks = (nrows + 127) >> 7;
    for (int chunk = blockIdx.x; chunk < nchunks; chunk += gridDim.x) {
        int row0 = chunk * 128 + rg * 8;
        const float* Ap[8];
#pragma unroll
        for (int r = 0; r < 8; ++r)
            Ap[r] = A + (size_t)min(row0 + r, nrows - 1) * CH;

        float acc[8][8];
#pragma unroll
        for (int r = 0; r < 8; ++r)
#pragma unroll
            for (int j = 0; j < 8; ++j) acc[r][j] = 0.f;

        for (int k = 0; k < CH; k += 4) {
            float4 a[8];
#pragma unroll
            for (int r = 0; r < 8; ++r) a[r] = ld4(Ap[r] + k);
            if (bnsc) {
                float4 sc = ld4(bnsc + k), sh = ld4(bnsc + CH + k);
#pragma unroll
                for (int r = 0; r < 8; ++r) {
                    a[r].x = fmaxf(fmaf(a[r].x, sc.x, sh.x), 0.f);
                    a[r].y = fmaxf(fmaf(a[r].y, sc.y, sh.y), 0.f);
                    a[r].z = fmaxf(fmaf(a[r].z, sc.z, sh.z), 0.f);
                    a[r].w = fmaxf(fmaf(a[r].w, sc.w, sh.w), 0.f);
                }
            }
#pragma unroll
            for (int kk = 0; kk < 4; ++kk) {
                float4 w0 = ld4(&Wl[(k + kk) * CH + cg * 8]);
                float4 w1 = ld4(&Wl[(k + kk) * CH + cg * 8 + 4]);
#pragma unroll
                for (int r = 0; r < 8; ++r) {
                    float e = f4get(a[r], kk);
                    acc[r][0] += e * w0.x; acc[r][1] += e * w0.y;
                    acc[r][2] += e * w0.z; acc[r][3] += e * w0.w;
                    acc[r][4] += e * w1.x; acc[r][5] += e * w1.y;
                    acc[r][6] += e * w1.z; acc[r][7] += e * w1.w;
                }
            }
        }

        __syncthreads();   // in-place safety
#pragma unroll
        for (int r = 0; r < 8; ++r) {
            int row = row0 + r;
            if (row < nrows) {
                float v[8];
#pragma unroll
                for (int j = 0; j < 8; ++j) {
                    float t = acc[r][j] + b8[j];
                    if (doRelu) t = fmaxf(t, 0.f);
                    v[j] = t;
                }
                if (doStats) {
#pragma unroll
                    for (int j = 0; j < 8; ++j) { ssum[j] += v[j]; ssq[j] += v[j] * v[j]; }
                }
                *reinterpret_cast<float4*>(&C[(size_t)row * CH + cg * 8]) =
                    make_float4(v[0], v[1], v[2], v[3]);
                *reinterpret_cast<float4*>(&C[(size_t)row * CH + cg * 8 + 4]) =
                    make_float4(v[4], v[5], v[6], v[7]);
            }
        }
    }

    if (doStats) {
#pragma unroll
        for (int j = 0; j < 8; ++j) {
            ssum[j] += __shfl_xor(ssum[j], 16, 64); ssum[j] += __shfl_xor(ssum[j], 32, 64);
            ssq[j]  += __shfl_xor(ssq[j], 16, 64);  ssq[j]  += __shfl_xor(ssq[j], 32, 64);
        }
        __syncthreads();
        float* red = Wl;
        int wv = tid >> 6, lane = tid & 63;
        if (lane < 16) {
#pragma unroll
            for (int j = 0; j < 8; ++j) {
                red[wv * 128 + lane * 8 + j] = ssum[j];
                red[512 + wv * 128 + lane * 8 + j] = ssq[j];
            }
        }
        __syncthreads();
        if (tid < 128) {
            float s = 0.f, q = 0.f;
#pragma unroll
            for (int w = 0; w < 4; ++w) { s += red[w * 128 + tid]; q += red[512 + w * 128 + tid]; }
            atomicAdd(&stats[tid], s);
            atomicAdd(&stats[128 + tid], q);
        }
    }
}

// ---------------- BN finalize ----------------
__global__ void k_bnfin(const float* __restrict__ stats, const float* __restrict__ gamma,
        const float* __restrict__ beta, float* __restrict__ scsh, float invN) {
    int c = threadIdx.x;
    if (c < CH) {
        float mean = stats[c] * invN;
        float var = stats[CH + c] * invN - mean * mean;   // biased, as in ref
        float sc = gamma[c] * rsqrtf(var + 1e-5f);
        scsh[c] = sc;
        scsh[CH + c] = beta[c] - mean * sc;
    }
}

extern "C" void kernel_launch(void* const* d_in, const int* in_sizes, int n_in,
                              void* d_out, int out_size, void* d_ws, size_t ws_size,
                              hipStream_t stream) {
    const float* x     = (const float*)d_in[0];
    const int*   ei    = (const int*)d_in[1];
    const float* W1    = (const float*)d_in[2];
    const float* b1    = (const float*)d_in[3];
    const float* gamma = (const float*)d_in[4];
    const float* beta  = (const float*)d_in[5];
    const float* W2    = (const float*)d_in[6];
    const float* b2    = (const float*)d_in[7];
    float* out = (float*)d_out;

    const int N = in_sizes[0] / CH;   // 100000
    const int E = in_sizes[1] / 2;    // 1600000
    const int* esrc = ei;
    const int* edst = ei + E;
    const int nbkt = (N + 63) >> 6;   // 1563
    const int chunkSz = (E + NCHUNK - 1) / NCHUNK;

    // H[NCHUNK][nbkt] (3.2MB) and sorted[E] (6.4MB) live in d_out's 51.2MB,
    // which is dead until k_aggregate_h overwrites it.
    int* H      = (int*)d_out;
    int* sorted = (int*)((char*)d_out + ((size_t)NCHUNK * nbkt * 4 + 255 & ~(size_t)255));

    char* w = (char*)d_ws;
    auto take = [&](size_t bytes) {
        char* p = w;
        w += (bytes + 255) & ~(size_t)255;
        return p;
    };
    int*      csr    = (int*)take((size_t)E * 4);
    int*      T      = (int*)take((size_t)(nbkt + 1) * 4);
    int*      base   = (int*)take((size_t)(nbkt + 1) * 4);
    int*      offs   = (int*)take((size_t)(N + 1) * 4);
    float*    stats  = (float*)take(256 * 4);
    float*    scsh   = (float*)take(256 * 4);
    uint32_t* xh     = (uint32_t*)take((size_t)N * CH * 2);   // fp16 copy of x
    bool useFp16 = ((size_t)(w - (char*)d_ws) <= ws_size);

    float* h = out;   // d_out becomes the [N][128] fp32 intermediate at aggregation

    hipMemsetAsync(stats, 0, 256 * 4, stream);

    k_bhist<<<NCHUNK, 256, 0, stream>>>(edst, H, E, nbkt, chunkSz);
    k_btot<<<nbkt, 256, 0, stream>>>(H, T, NCHUNK, nbkt);
    k_bscan<<<1, 1024, 0, stream>>>(T, base, nbkt);
    k_boff<<<nbkt, NCHUNK, 0, stream>>>(H, base, NCHUNK, nbkt);
    k_bscatter<<<NCHUNK, 256, 0, stream>>>(esrc, edst, H, sorted, E, nbkt, chunkSz);
    k_bsort2<<<nbkt, 256, 0, stream>>>(sorted, base, csr, offs, N, nbkt, E);
    if (useFp16) {
        k_tofp16<<<2048, 256, 0, stream>>>(x, xh, N * CH / 8);
        k_aggregate_h<<<4096, 256, 0, stream>>>(x, (const __half2*)xh, csr, offs, h, N);
    } else {
        k_aggregate<<<4096, 256, 0, stream>>>(x, csr, offs, h, N);
    }
    k_gemm128<<<512, 256, 0, stream>>>(h, W1, b1, h, stats, nullptr, N, 1, 0);
    k_bnfin<<<1, 128, 0, stream>>>(stats, gamma, beta, scsh, 1.0f / (float)N);
    k_gemm128<<<512, 256, 0, stream>>>(h, W2, b2, out, nullptr, scsh, N, 0, 1);
}

// Round 6
// 211.767 us; speedup vs baseline: 6.6137x; 1.4629x over previous
//
#include <hip/hip_runtime.h>
#include <hip/hip_bf16.h>
#include <hip/hip_fp16.h>
#include <stdint.h>

#define CH 128
#define NCHUNK 512          // edge chunks for counting sort
#define MAXBKT 2048         // >= ceil(N/64)

typedef _Float16 f16x8 __attribute__((ext_vector_type(8)));
typedef float f32x4 __attribute__((ext_vector_type(4)));

static __device__ __forceinline__ float4 ld4(const float* p) {
    return *reinterpret_cast<const float4*>(p);
}

// ---------------- phase 1: per-chunk bucket histograms (LDS atomics only) ----------
__global__ void k_bhist(const int* __restrict__ dst, int* __restrict__ H,
                        int nE, int nbkt, int chunkSz) {
    __shared__ int hist[MAXBKT];
    int c = blockIdx.x, tid = threadIdx.x;
    for (int i = tid; i < nbkt; i += 256) hist[i] = 0;
    __syncthreads();
    int s = c * chunkSz, e = min(s + chunkSz, nE);
    for (int i = s + tid; i < e; i += 256) atomicAdd(&hist[dst[i] >> 6], 1);
    __syncthreads();
    for (int i = tid; i < nbkt; i += 256) H[c * nbkt + i] = hist[i];
}

// ---------------- phase 2a: per-bucket totals ----------
__global__ void k_btot(const int* __restrict__ H, int* __restrict__ T, int nchunk, int nbkt) {
    __shared__ int sd[256];
    int b = blockIdx.x, tid = threadIdx.x;
    int v = 0;
    for (int c = tid; c < nchunk; c += 256) v += H[c * nbkt + b];
    sd[tid] = v;
    __syncthreads();
    for (int o = 128; o > 0; o >>= 1) {
        if (tid < o) sd[tid] += sd[tid + o];
        __syncthreads();
    }
    if (tid == 0) T[b] = sd[0];
}

// ---------------- phase 2b: exclusive scan of bucket totals -> base ----------
__global__ __launch_bounds__(1024) void k_bscan(const int* __restrict__ T,
                                                int* __restrict__ base, int nbkt) {
    __shared__ int ps[1024];
    int t = threadIdx.x;
    int a0 = (2 * t < nbkt) ? T[2 * t] : 0;
    int a1 = (2 * t + 1 < nbkt) ? T[2 * t + 1] : 0;
    ps[t] = a0 + a1;
    __syncthreads();
    for (int d = 1; d < 1024; d <<= 1) {
        int v = (t >= d) ? ps[t - d] : 0;
        __syncthreads();
        ps[t] += v;
        __syncthreads();
    }
    int excl = t ? ps[t - 1] : 0;
    if (2 * t < nbkt) base[2 * t] = excl;
    if (2 * t + 1 < nbkt) base[2 * t + 1] = excl + a0;
    if (t == 0) base[nbkt] = ps[1023];
}

// ---------------- phase 2c: per-(chunk,bucket) offsets, in place over H ----------
__global__ __launch_bounds__(512) void k_boff(int* H, const int* __restrict__ base,
                                              int nchunk, int nbkt) {
    __shared__ int sd[NCHUNK];
    int b = blockIdx.x, t = threadIdx.x;
    int v = (t < nchunk) ? H[t * nbkt + b] : 0;
    sd[t] = v;
    __syncthreads();
    for (int d = 1; d < NCHUNK; d <<= 1) {
        int tv = (t >= d) ? sd[t - d] : 0;
        __syncthreads();
        sd[t] += tv;
        __syncthreads();
    }
    if (t < nchunk) H[t * nbkt + b] = base[b] + sd[t] - v;
}

// ---------------- phase 3: bucket scatter (LDS cursors, plain global stores) ------
__global__ void k_bscatter(const int* __restrict__ src, const int* __restrict__ dst,
                           const int* __restrict__ H, int* __restrict__ sorted,
                           int nE, int nbkt, int chunkSz) {
    __shared__ int cur[MAXBKT];
    int c = blockIdx.x, tid = threadIdx.x;
    for (int i = tid; i < nbkt; i += 256) cur[i] = H[c * nbkt + i];
    __syncthreads();
    int s = c * chunkSz, e = min(s + chunkSz, nE);
    for (int i = s + tid; i < e; i += 256) {
        int d = dst[i];
        int pos = atomicAdd(&cur[d >> 6], 1);
        sorted[pos] = src[i] | ((d & 63) << 17);
    }
}

// ---------------- phase 4: within-bucket sort -> per-node CSR + offs ----------
__global__ __launch_bounds__(256) void k_bsort2(const int* __restrict__ sorted,
        const int* __restrict__ base, int* __restrict__ csr, int* __restrict__ offs,
        int n, int nbkt, int nE) {
    __shared__ int hist[64];
    __shared__ int cur[64];
    int b = blockIdx.x, tid = threadIdx.x;
    if (tid < 64) hist[tid] = 0;
    __syncthreads();
    int s = base[b], e = base[b + 1];
    for (int i = s + tid; i < e; i += 256)
        atomicAdd(&hist[(sorted[i] >> 17) & 63], 1);
    __syncthreads();
    if (tid < 64) {
        int h0 = hist[tid];
        int v = h0;
        for (int d = 1; d < 64; d <<= 1) {
            int t = __shfl_up(v, d, 64);
            if (tid >= d) v += t;
        }
        int excl = base[b] + v - h0;
        int node = b * 64 + tid;
        if (node < n) offs[node] = excl;
        cur[tid] = excl;
    }
    if (b == 0 && tid == 0) offs[n] = nE;
    __syncthreads();
    for (int i = s + tid; i < e; i += 256) {
        int p = sorted[i];
        int pos = atomicAdd(&cur[(p >> 17) & 63], 1);
        csr[pos] = p & 0x1FFFF;
    }
}

// ---------------- x -> fp16 copy ----------------
__global__ void k_tofp16(const float* __restrict__ x, uint32_t* __restrict__ xh, int n8) {
    int i = blockIdx.x * blockDim.x + threadIdx.x;
    int st = gridDim.x * blockDim.x;
    for (; i < n8; i += st) {
        float4 v0 = ld4(x + (size_t)i * 8);
        float4 v1 = ld4(x + (size_t)i * 8 + 4);
        __half2 h0 = __floats2half2_rn(v0.x, v0.y);
        __half2 h1 = __floats2half2_rn(v0.z, v0.w);
        __half2 h2 = __floats2half2_rn(v1.x, v1.y);
        __half2 h3 = __floats2half2_rn(v1.z, v1.w);
        uint4 o;
        o.x = *reinterpret_cast<unsigned*>(&h0);
        o.y = *reinterpret_cast<unsigned*>(&h1);
        o.z = *reinterpret_cast<unsigned*>(&h2);
        o.w = *reinterpret_cast<unsigned*>(&h3);
        reinterpret_cast<uint4*>(xh)[i] = o;
    }
}

// ---------------- GIN aggregate (fp16 gather) -> fp16 h ----------------
// h16[i] = fp16(x[i] + sum_j xh[src_j]); one wave per node, fp32 accum.
__global__ void k_aggregate_h(const float* __restrict__ x, const __half2* __restrict__ xh,
        const int* __restrict__ csr, const int* __restrict__ offs,
        uint32_t* __restrict__ h16, int n) {
    int wid = (blockIdx.x * blockDim.x + threadIdx.x) >> 6;
    int lane = threadIdx.x & 63;
    int nw = (gridDim.x * blockDim.x) >> 6;
    for (int node = wid; node < n; node += nw) {
        float2 a0 = *reinterpret_cast<const float2*>(&x[(size_t)node * CH + lane * 2]);
        float2 a1 = make_float2(0.f, 0.f), a2 = make_float2(0.f, 0.f), a3 = make_float2(0.f, 0.f);
        int s = offs[node], e = offs[node + 1];
        int i = s;
        for (; i + 3 < e; i += 4) {
            int s0 = csr[i], s1 = csr[i + 1], s2 = csr[i + 2], s3 = csr[i + 3];
            float2 v0 = __half22float2(xh[(size_t)s0 * 64 + lane]);
            float2 v1 = __half22float2(xh[(size_t)s1 * 64 + lane]);
            float2 v2 = __half22float2(xh[(size_t)s2 * 64 + lane]);
            float2 v3 = __half22float2(xh[(size_t)s3 * 64 + lane]);
            a0.x += v0.x; a0.y += v0.y;
            a1.x += v1.x; a1.y += v1.y;
            a2.x += v2.x; a2.y += v2.y;
            a3.x += v3.x; a3.y += v3.y;
        }
        for (; i < e; ++i) {
            float2 v0 = __half22float2(xh[(size_t)csr[i] * 64 + lane]);
            a0.x += v0.x; a0.y += v0.y;
        }
        a0.x += a1.x + a2.x + a3.x;
        a0.y += a1.y + a2.y + a3.y;
        __half2 hv = __floats2half2_rn(a0.x, a0.y);
        h16[(size_t)node * 64 + lane] = *reinterpret_cast<unsigned*>(&hv);
    }
}

// ---------------- MFMA GEMM: [nrows x 128] fp16 @ [128 x 128] -> out ----------------
// v_mfma_f32_16x16x32_f16. W^T staged in LDS as fp16 with 16B-slot XOR swizzle
// (slot ^= col&7) so B-frag ds_read_b128 hits all 32 banks.
// doStats: fp16 out (pre-BN h1) + per-channel sum/sumsq atomics.
// bnsc   : A-load is relu(a*sc[k]+sh[k]) (GEMM2); fp32 out with final relu.
__global__ __launch_bounds__(256) void k_mgemm(
        const _Float16* __restrict__ A, const float* __restrict__ W,
        const float* __restrict__ bias, _Float16* __restrict__ O16,
        float* __restrict__ O32, float* __restrict__ stats,
        const float* __restrict__ bnsc, int nrows, int doStats) {
    __shared__ _Float16 WT[CH * CH];   // 32 KiB, swizzled
    __shared__ float sc_sh[2 * CH];
    int tid = threadIdx.x;
    for (int idx = tid; idx < CH * CH; idx += 256) {
        int k = idx >> 7, col = idx & 127;
        int s = k >> 3, j = k & 7;
        WT[col * CH + ((s ^ (col & 7)) << 3) + j] = (_Float16)W[idx];
    }
    if (bnsc && tid < 2 * CH) sc_sh[tid] = bnsc[tid];
    __syncthreads();

    int wv = tid >> 6, lane = tid & 63;
    int lr = lane & 15;   // A-row / B-col / D-col within tile
    int lg = lane >> 4;   // k-group 0..3 (and D row-group)

    float bv[8];
#pragma unroll
    for (int ct = 0; ct < 8; ++ct) bv[ct] = bias[ct * 16 + lr];
    float ssum[8], ssq[8];
#pragma unroll
    for (int ct = 0; ct < 8; ++ct) { ssum[ct] = 0.f; ssq[ct] = 0.f; }

    int nchunks = (nrows + 63) >> 6;
    for (int chunk = blockIdx.x; chunk < nchunks; chunk += gridDim.x) {
        int row0 = chunk * 64 + wv * 16;
        int arow = min(row0 + lr, nrows - 1);
        const _Float16* Ap = A + (size_t)arow * CH + lg * 8;
        f16x8 a[4];
#pragma unroll
        for (int kb = 0; kb < 4; ++kb)
            a[kb] = *reinterpret_cast<const f16x8*>(Ap + kb * 32);
        if (bnsc) {
#pragma unroll
            for (int kb = 0; kb < 4; ++kb) {
                int k0 = kb * 32 + lg * 8;
#pragma unroll
                for (int j = 0; j < 8; ++j) {
                    float f = (float)a[kb][j];
                    f = fmaxf(fmaf(f, sc_sh[k0 + j], sc_sh[CH + k0 + j]), 0.f);
                    a[kb][j] = (_Float16)f;
                }
            }
        }

        f32x4 acc[8];
#pragma unroll
        for (int ct = 0; ct < 8; ++ct) acc[ct] = (f32x4){0.f, 0.f, 0.f, 0.f};
#pragma unroll
        for (int ct = 0; ct < 8; ++ct) {
            int col = ct * 16 + lr;
            const _Float16* Wp = &WT[col * CH];
            int sw = (col & 7) << 3;
#pragma unroll
            for (int kb = 0; kb < 4; ++kb) {
                int s = kb * 4 + lg;
                f16x8 b = *reinterpret_cast<const f16x8*>(Wp + ((s << 3) ^ sw));
                acc[ct] = __builtin_amdgcn_mfma_f32_16x16x32_f16(a[kb], b, acc[ct], 0, 0, 0);
            }
        }

        // epilogue: D col = ct*16+lr, row = row0 + lg*4 + r
#pragma unroll
        for (int ct = 0; ct < 8; ++ct) {
            int col = ct * 16 + lr;
#pragma unroll
            for (int r = 0; r < 4; ++r) {
                int row = row0 + lg * 4 + r;
                if (row < nrows) {
                    float v = acc[ct][r] + bv[ct];
                    if (doStats) {
                        O16[(size_t)row * CH + col] = (_Float16)v;
                        ssum[ct] += v;
                        ssq[ct] += v * v;
                    } else {
                        O32[(size_t)row * CH + col] = fmaxf(v, 0.f);
                    }
                }
            }
        }
    }

    if (doStats) {
#pragma unroll
        for (int ct = 0; ct < 8; ++ct) {
            ssum[ct] += __shfl_xor(ssum[ct], 16, 64); ssum[ct] += __shfl_xor(ssum[ct], 32, 64);
            ssq[ct]  += __shfl_xor(ssq[ct], 16, 64);  ssq[ct]  += __shfl_xor(ssq[ct], 32, 64);
        }
        __syncthreads();           // WT dead; reuse as reduce scratch
        float* red = (float*)WT;   // [4][128] sums + [4][128] sqs = 4KB
        if (lg == 0) {
#pragma unroll
            for (int ct = 0; ct < 8; ++ct) {
                red[wv * 128 + ct * 16 + lr] = ssum[ct];
                red[512 + wv * 128 + ct * 16 + lr] = ssq[ct];
            }
        }
        __syncthreads();
        if (tid < 128) {
            float s = 0.f, q = 0.f;
#pragma unroll
            for (int w = 0; w < 4; ++w) { s += red[w * 128 + tid]; q += red[512 + w * 128 + tid]; }
            atomicAdd(&stats[tid], s);
            atomicAdd(&stats[128 + tid], q);
        }
    }
}

// ---------------- BN finalize ----------------
__global__ void k_bnfin(const float* __restrict__ stats, const float* __restrict__ gamma,
        const float* __restrict__ beta, float* __restrict__ scsh, float invN) {
    int c = threadIdx.x;
    if (c < CH) {
        float mean = stats[c] * invN;
        float var = stats[CH + c] * invN - mean * mean;   // biased, as in ref
        float sc = gamma[c] * rsqrtf(var + 1e-5f);
        scsh[c] = sc;
        scsh[CH + c] = beta[c] - mean * sc;
    }
}

extern "C" void kernel_launch(void* const* d_in, const int* in_sizes, int n_in,
                              void* d_out, int out_size, void* d_ws, size_t ws_size,
                              hipStream_t stream) {
    const float* x     = (const float*)d_in[0];
    const int*   ei    = (const int*)d_in[1];
    const float* W1    = (const float*)d_in[2];
    const float* b1    = (const float*)d_in[3];
    const float* gamma = (const float*)d_in[4];
    const float* beta  = (const float*)d_in[5];
    const float* W2    = (const float*)d_in[6];
    const float* b2    = (const float*)d_in[7];

    const int N = in_sizes[0] / CH;   // 100000
    const int E = in_sizes[1] / 2;    // 1600000
    const int* esrc = ei;
    const int* edst = ei + E;
    const int nbkt = (N + 63) >> 6;   // 1563
    const int chunkSz = (E + NCHUNK - 1) / NCHUNK;

    // d_out (51.2MB fp32) is dead until the end; reuse it:
    //   [0..3.2MB)  H[NCHUNK][nbkt]   (dead after k_bscatter)
    //   [3.2..9.6MB) sorted[E]        (dead after k_bsort2)
    //   [0..25.6MB) h16 fp16          (written by aggregate, read by GEMM1)
    //   final: full fp32 output       (written by GEMM2)
    int* H      = (int*)d_out;
    int* sorted = (int*)((char*)d_out + (((size_t)NCHUNK * nbkt * 4 + 255) & ~(size_t)255));
    _Float16* h16 = (_Float16*)d_out;

    char* w = (char*)d_ws;
    auto take = [&](size_t bytes) {
        char* p = w;
        w += (bytes + 255) & ~(size_t)255;
        return p;
    };
    int*      csr    = (int*)take((size_t)E * 4);
    int*      T      = (int*)take((size_t)(nbkt + 1) * 4);
    int*      base   = (int*)take((size_t)(nbkt + 1) * 4);
    int*      offs   = (int*)take((size_t)(N + 1) * 4);
    float*    stats  = (float*)take(256 * 4);
    float*    scsh   = (float*)take(256 * 4);
    uint32_t* xh     = (uint32_t*)take((size_t)N * CH * 2);   // fp16 x; reused as h1 after aggregate
    _Float16* h1     = (_Float16*)xh;

    hipMemsetAsync(stats, 0, 256 * 4, stream);

    k_bhist<<<NCHUNK, 256, 0, stream>>>(edst, H, E, nbkt, chunkSz);
    k_btot<<<nbkt, 256, 0, stream>>>(H, T, NCHUNK, nbkt);
    k_bscan<<<1, 1024, 0, stream>>>(T, base, nbkt);
    k_boff<<<nbkt, NCHUNK, 0, stream>>>(H, base, NCHUNK, nbkt);
    k_bscatter<<<NCHUNK, 256, 0, stream>>>(esrc, edst, H, sorted, E, nbkt, chunkSz);
    k_bsort2<<<nbkt, 256, 0, stream>>>(sorted, base, csr, offs, N, nbkt, E);
    k_tofp16<<<2048, 256, 0, stream>>>(x, xh, N * CH / 8);
    k_aggregate_h<<<4096, 256, 0, stream>>>(x, (const __half2*)xh, csr, offs,
                                            (uint32_t*)h16, N);
    // GEMM1: h16 @ W1 + b1 -> h1 (fp16, pre-BN) + channel stats
    k_mgemm<<<512, 256, 0, stream>>>(h16, W1, b1, h1, nullptr, stats, nullptr, N, 1);
    k_bnfin<<<1, 128, 0, stream>>>(stats, gamma, beta, scsh, 1.0f / (float)N);
    // GEMM2: relu(BN(h1)) @ W2 + b2 -> relu -> fp32 out
    k_mgemm<<<512, 256, 0, stream>>>(h1, W2, b2, nullptr, (float*)d_out, nullptr, scsh, N, 0);
}

// Round 7
// 210.075 us; speedup vs baseline: 6.6670x; 1.0081x over previous
//
#include <hip/hip_runtime.h>
#include <hip/hip_bf16.h>
#include <hip/hip_fp16.h>
#include <stdint.h>

#define CH 128
#define NCHUNK 512          // edge chunks for counting sort
#define MAXBKT 2048         // >= ceil(N/64)

typedef _Float16 f16x8 __attribute__((ext_vector_type(8)));
typedef float f32x4 __attribute__((ext_vector_type(4)));

static __device__ __forceinline__ float4 ld4(const float* p) {
    return *reinterpret_cast<const float4*>(p);
}

// ---------------- phase 1: per-chunk bucket histograms (LDS atomics only) ----------
__global__ void k_bhist(const int* __restrict__ dst, int* __restrict__ H,
                        int nE, int nbkt, int chunkSz) {
    __shared__ int hist[MAXBKT];
    int c = blockIdx.x, tid = threadIdx.x;
    for (int i = tid; i < nbkt; i += 256) hist[i] = 0;
    __syncthreads();
    int s = c * chunkSz, e = min(s + chunkSz, nE);
    for (int i = s + tid; i < e; i += 256) atomicAdd(&hist[dst[i] >> 6], 1);
    __syncthreads();
    for (int i = tid; i < nbkt; i += 256) H[c * nbkt + i] = hist[i];
}

// ---------------- phase 2a: per-bucket totals ----------
__global__ void k_btot(const int* __restrict__ H, int* __restrict__ T, int nchunk, int nbkt) {
    __shared__ int sd[256];
    int b = blockIdx.x, tid = threadIdx.x;
    int v = 0;
    for (int c = tid; c < nchunk; c += 256) v += H[c * nbkt + b];
    sd[tid] = v;
    __syncthreads();
    for (int o = 128; o > 0; o >>= 1) {
        if (tid < o) sd[tid] += sd[tid + o];
        __syncthreads();
    }
    if (tid == 0) T[b] = sd[0];
}

// ---------------- phase 2b: exclusive scan of bucket totals -> base ----------
__global__ __launch_bounds__(1024) void k_bscan(const int* __restrict__ T,
                                                int* __restrict__ base, int nbkt) {
    __shared__ int ps[1024];
    int t = threadIdx.x;
    int a0 = (2 * t < nbkt) ? T[2 * t] : 0;
    int a1 = (2 * t + 1 < nbkt) ? T[2 * t + 1] : 0;
    ps[t] = a0 + a1;
    __syncthreads();
    for (int d = 1; d < 1024; d <<= 1) {
        int v = (t >= d) ? ps[t - d] : 0;
        __syncthreads();
        ps[t] += v;
        __syncthreads();
    }
    int excl = t ? ps[t - 1] : 0;
    if (2 * t < nbkt) base[2 * t] = excl;
    if (2 * t + 1 < nbkt) base[2 * t + 1] = excl + a0;
    if (t == 0) base[nbkt] = ps[1023];
}

// ---------------- phase 2c: per-(chunk,bucket) offsets, in place over H ----------
__global__ __launch_bounds__(512) void k_boff(int* H, const int* __restrict__ base,
                                              int nchunk, int nbkt) {
    __shared__ int sd[NCHUNK];
    int b = blockIdx.x, t = threadIdx.x;
    int v = (t < nchunk) ? H[t * nbkt + b] : 0;
    sd[t] = v;
    __syncthreads();
    for (int d = 1; d < NCHUNK; d <<= 1) {
        int tv = (t >= d) ? sd[t - d] : 0;
        __syncthreads();
        sd[t] += tv;
        __syncthreads();
    }
    if (t < nchunk) H[t * nbkt + b] = base[b] + sd[t] - v;
}

// ---------------- phase 3: bucket scatter (LDS cursors, plain global stores) ------
__global__ void k_bscatter(const int* __restrict__ src, const int* __restrict__ dst,
                           const int* __restrict__ H, int* __restrict__ sorted,
                           int nE, int nbkt, int chunkSz) {
    __shared__ int cur[MAXBKT];
    int c = blockIdx.x, tid = threadIdx.x;
    for (int i = tid; i < nbkt; i += 256) cur[i] = H[c * nbkt + i];
    __syncthreads();
    int s = c * chunkSz, e = min(s + chunkSz, nE);
    for (int i = s + tid; i < e; i += 256) {
        int d = dst[i];
        int pos = atomicAdd(&cur[d >> 6], 1);
        sorted[pos] = src[i] | ((d & 63) << 17);
    }
}

// ---------------- phase 4: within-bucket sort -> per-node CSR + offs ----------
__global__ __launch_bounds__(256) void k_bsort2(const int* __restrict__ sorted,
        const int* __restrict__ base, int* __restrict__ csr, int* __restrict__ offs,
        int n, int nbkt, int nE) {
    __shared__ int hist[64];
    __shared__ int cur[64];
    int b = blockIdx.x, tid = threadIdx.x;
    if (tid < 64) hist[tid] = 0;
    __syncthreads();
    int s = base[b], e = base[b + 1];
    for (int i = s + tid; i < e; i += 256)
        atomicAdd(&hist[(sorted[i] >> 17) & 63], 1);
    __syncthreads();
    if (tid < 64) {
        int h0 = hist[tid];
        int v = h0;
        for (int d = 1; d < 64; d <<= 1) {
            int t = __shfl_up(v, d, 64);
            if (tid >= d) v += t;
        }
        int excl = base[b] + v - h0;
        int node = b * 64 + tid;
        if (node < n) offs[node] = excl;
        cur[tid] = excl;
    }
    if (b == 0 && tid == 0) offs[n] = nE;
    __syncthreads();
    for (int i = s + tid; i < e; i += 256) {
        int p = sorted[i];
        int pos = atomicAdd(&cur[(p >> 17) & 63], 1);
        csr[pos] = p & 0x1FFFF;
    }
}

// ---------------- x -> fp16 copy ----------------
__global__ void k_tofp16(const float* __restrict__ x, uint32_t* __restrict__ xh, int n8) {
    int i = blockIdx.x * blockDim.x + threadIdx.x;
    int st = gridDim.x * blockDim.x;
    for (; i < n8; i += st) {
        float4 v0 = ld4(x + (size_t)i * 8);
        float4 v1 = ld4(x + (size_t)i * 8 + 4);
        __half2 h0 = __floats2half2_rn(v0.x, v0.y);
        __half2 h1 = __floats2half2_rn(v0.z, v0.w);
        __half2 h2 = __floats2half2_rn(v1.x, v1.y);
        __half2 h3 = __floats2half2_rn(v1.z, v1.w);
        uint4 o;
        o.x = *reinterpret_cast<unsigned*>(&h0);
        o.y = *reinterpret_cast<unsigned*>(&h1);
        o.z = *reinterpret_cast<unsigned*>(&h2);
        o.w = *reinterpret_cast<unsigned*>(&h3);
        reinterpret_cast<uint4*>(xh)[i] = o;
    }
}

static __device__ __forceinline__ void acc4(float4& a, uint2 v) {
    __half2 p0 = *reinterpret_cast<__half2*>(&v.x);
    __half2 p1 = *reinterpret_cast<__half2*>(&v.y);
    float2 f0 = __half22float2(p0), f1 = __half22float2(p1);
    a.x += f0.x; a.y += f0.y; a.z += f1.x; a.w += f1.y;
}

// ---------------- GIN aggregate, 2 edges/wave, 8B/lane ----------------
// lanes 0-31 take even edges, 32-63 odd; lane handles 4 fp16 channels (uint2).
// fp32 accumulate, shfl_xor(32) cross-half combine, fp16 output row.
__global__ void k_aggregate_h2(const uint2* __restrict__ xv,
        const int* __restrict__ csr, const int* __restrict__ offs,
        uint2* __restrict__ h16, int n) {
    int wid = (blockIdx.x * blockDim.x + threadIdx.x) >> 6;
    int lane = threadIdx.x & 63;
    int nw = (gridDim.x * blockDim.x) >> 6;
    int hf = lane >> 5;
    int l32 = lane & 31;
    for (int node = wid; node < n; node += nw) {
        float4 a0 = make_float4(0.f, 0.f, 0.f, 0.f), a1 = a0, a2 = a0, a3 = a0;
        if (hf == 0) acc4(a0, xv[(size_t)node * 32 + l32]);   // self-term (fp16 x)
        int s = offs[node], e = offs[node + 1];
        int i = s + hf;
        for (; i + 6 < e; i += 8) {
            int e0 = csr[i], e1 = csr[i + 2], e2 = csr[i + 4], e3 = csr[i + 6];
            uint2 v0 = xv[(size_t)e0 * 32 + l32];
            uint2 v1 = xv[(size_t)e1 * 32 + l32];
            uint2 v2 = xv[(size_t)e2 * 32 + l32];
            uint2 v3 = xv[(size_t)e3 * 32 + l32];
            acc4(a0, v0); acc4(a1, v1); acc4(a2, v2); acc4(a3, v3);
        }
        for (; i < e; i += 2)
            acc4(a0, xv[(size_t)csr[i] * 32 + l32]);
        a0.x += a1.x + a2.x + a3.x;
        a0.y += a1.y + a2.y + a3.y;
        a0.z += a1.z + a2.z + a3.z;
        a0.w += a1.w + a2.w + a3.w;
        a0.x += __shfl_xor(a0.x, 32, 64);
        a0.y += __shfl_xor(a0.y, 32, 64);
        a0.z += __shfl_xor(a0.z, 32, 64);
        a0.w += __shfl_xor(a0.w, 32, 64);
        if (hf == 0) {
            __half2 o0 = __floats2half2_rn(a0.x, a0.y);
            __half2 o1 = __floats2half2_rn(a0.z, a0.w);
            uint2 ov;
            ov.x = *reinterpret_cast<unsigned*>(&o0);
            ov.y = *reinterpret_cast<unsigned*>(&o1);
            h16[(size_t)node * 32 + l32] = ov;
        }
    }
}

// ---------------- MFMA GEMM: [nrows x 128] fp16 @ [128 x 128] -> out ----------------
// v_mfma_f32_16x16x32_f16. W^T staged in LDS as fp16 with 16B-slot XOR swizzle
// (slot ^= col&7) so B-frag ds_read_b128 hits all 32 banks.
__global__ __launch_bounds__(256) void k_mgemm(
        const _Float16* __restrict__ A, const float* __restrict__ W,
        const float* __restrict__ bias, _Float16* __restrict__ O16,
        float* __restrict__ O32, float* __restrict__ stats,
        const float* __restrict__ bnsc, int nrows, int doStats) {
    __shared__ _Float16 WT[CH * CH];   // 32 KiB, swizzled
    __shared__ float sc_sh[2 * CH];
    int tid = threadIdx.x;
    for (int idx4 = tid * 4; idx4 < CH * CH; idx4 += 1024) {
        float4 wv = ld4(W + idx4);
        int k = idx4 >> 7, col = idx4 & 127;    // 4 consecutive cols, same k
        int s = k >> 3, j = k & 7;
#pragma unroll
        for (int q = 0; q < 4; ++q) {
            int c = col + q;
            WT[c * CH + ((s ^ (c & 7)) << 3) + j] =
                (_Float16)(q == 0 ? wv.x : q == 1 ? wv.y : q == 2 ? wv.z : wv.w);
        }
    }
    if (bnsc && tid < 2 * CH) sc_sh[tid] = bnsc[tid];
    __syncthreads();

    int wv = tid >> 6, lane = tid & 63;
    int lr = lane & 15;   // A-row / B-col / D-col within tile
    int lg = lane >> 4;   // k-group 0..3 (and D row-group)

    float bv[8];
#pragma unroll
    for (int ct = 0; ct < 8; ++ct) bv[ct] = bias[ct * 16 + lr];
    float ssum[8], ssq[8];
#pragma unroll
    for (int ct = 0; ct < 8; ++ct) { ssum[ct] = 0.f; ssq[ct] = 0.f; }

    int nchunks = (nrows + 63) >> 6;
    for (int chunk = blockIdx.x; chunk < nchunks; chunk += gridDim.x) {
        int row0 = chunk * 64 + wv * 16;
        int arow = min(row0 + lr, nrows - 1);
        const _Float16* Ap = A + (size_t)arow * CH + lg * 8;
        f16x8 a[4];
#pragma unroll
        for (int kb = 0; kb < 4; ++kb)
            a[kb] = *reinterpret_cast<const f16x8*>(Ap + kb * 32);
        if (bnsc) {
#pragma unroll
            for (int kb = 0; kb < 4; ++kb) {
                int k0 = kb * 32 + lg * 8;
#pragma unroll
                for (int j = 0; j < 8; ++j) {
                    float f = (float)a[kb][j];
                    f = fmaxf(fmaf(f, sc_sh[k0 + j], sc_sh[CH + k0 + j]), 0.f);
                    a[kb][j] = (_Float16)f;
                }
            }
        }

        f32x4 acc[8];
#pragma unroll
        for (int ct = 0; ct < 8; ++ct) acc[ct] = (f32x4){0.f, 0.f, 0.f, 0.f};
#pragma unroll
        for (int ct = 0; ct < 8; ++ct) {
            int col = ct * 16 + lr;
            const _Float16* Wp = &WT[col * CH];
            int sw = (col & 7) << 3;
#pragma unroll
            for (int kb = 0; kb < 4; ++kb) {
                int s = kb * 4 + lg;
                f16x8 b = *reinterpret_cast<const f16x8*>(Wp + ((s << 3) ^ sw));
                acc[ct] = __builtin_amdgcn_mfma_f32_16x16x32_f16(a[kb], b, acc[ct], 0, 0, 0);
            }
        }

        // epilogue: D col = ct*16+lr, row = row0 + lg*4 + r
#pragma unroll
        for (int ct = 0; ct < 8; ++ct) {
            int col = ct * 16 + lr;
#pragma unroll
            for (int r = 0; r < 4; ++r) {
                int row = row0 + lg * 4 + r;
                if (row < nrows) {
                    float v = acc[ct][r] + bv[ct];
                    if (doStats) {
                        O16[(size_t)row * CH + col] = (_Float16)v;
                        ssum[ct] += v;
                        ssq[ct] += v * v;
                    } else {
                        O32[(size_t)row * CH + col] = fmaxf(v, 0.f);
                    }
                }
            }
        }
    }

    if (doStats) {
#pragma unroll
        for (int ct = 0; ct < 8; ++ct) {
            ssum[ct] += __shfl_xor(ssum[ct], 16, 64); ssum[ct] += __shfl_xor(ssum[ct], 32, 64);
            ssq[ct]  += __shfl_xor(ssq[ct], 16, 64);  ssq[ct]  += __shfl_xor(ssq[ct], 32, 64);
        }
        __syncthreads();           // WT dead; reuse as reduce scratch
        float* red = (float*)WT;
        if (lg == 0) {
#pragma unroll
            for (int ct = 0; ct < 8; ++ct) {
                red[wv * 128 + ct * 16 + lr] = ssum[ct];
                red[512 + wv * 128 + ct * 16 + lr] = ssq[ct];
            }
        }
        __syncthreads();
        if (tid < 128) {
            float s = 0.f, q = 0.f;
#pragma unroll
            for (int w = 0; w < 4; ++w) { s += red[w * 128 + tid]; q += red[512 + w * 128 + tid]; }
            atomicAdd(&stats[tid], s);
            atomicAdd(&stats[128 + tid], q);
        }
    }
}

// ---------------- BN finalize ----------------
__global__ void k_bnfin(const float* __restrict__ stats, const float* __restrict__ gamma,
        const float* __restrict__ beta, float* __restrict__ scsh, float invN) {
    int c = threadIdx.x;
    if (c < CH) {
        float mean = stats[c] * invN;
        float var = stats[CH + c] * invN - mean * mean;   // biased, as in ref
        float sc = gamma[c] * rsqrtf(var + 1e-5f);
        scsh[c] = sc;
        scsh[CH + c] = beta[c] - mean * sc;
    }
}

extern "C" void kernel_launch(void* const* d_in, const int* in_sizes, int n_in,
                              void* d_out, int out_size, void* d_ws, size_t ws_size,
                              hipStream_t stream) {
    const float* x     = (const float*)d_in[0];
    const int*   ei    = (const int*)d_in[1];
    const float* W1    = (const float*)d_in[2];
    const float* b1    = (const float*)d_in[3];
    const float* gamma = (const float*)d_in[4];
    const float* beta  = (const float*)d_in[5];
    const float* W2    = (const float*)d_in[6];
    const float* b2    = (const float*)d_in[7];

    const int N = in_sizes[0] / CH;   // 100000
    const int E = in_sizes[1] / 2;    // 1600000
    const int* esrc = ei;
    const int* edst = ei + E;
    const int nbkt = (N + 63) >> 6;   // 1563
    const int chunkSz = (E + NCHUNK - 1) / NCHUNK;

    // d_out (51.2MB fp32) is dead until the end; reuse it:
    //   [0..3.2MB)  H[NCHUNK][nbkt]   (dead after k_bscatter)
    //   [3.2..9.6MB) sorted[E]        (dead after k_bsort2)
    //   [0..25.6MB) h16 fp16          (written by aggregate, read by GEMM1)
    //   final: full fp32 output       (written by GEMM2)
    int* H      = (int*)d_out;
    int* sorted = (int*)((char*)d_out + (((size_t)NCHUNK * nbkt * 4 + 255) & ~(size_t)255));
    _Float16* h16 = (_Float16*)d_out;

    char* w = (char*)d_ws;
    auto take = [&](size_t bytes) {
        char* p = w;
        w += (bytes + 255) & ~(size_t)255;
        return p;
    };
    int*      csr    = (int*)take((size_t)E * 4);
    int*      T      = (int*)take((size_t)(nbkt + 1) * 4);
    int*      base   = (int*)take((size_t)(nbkt + 1) * 4);
    int*      offs   = (int*)take((size_t)(N + 1) * 4);
    float*    stats  = (float*)take(256 * 4);
    float*    scsh   = (float*)take(256 * 4);
    uint32_t* xh     = (uint32_t*)take((size_t)N * CH * 2);   // fp16 x; reused as h1 after aggregate
    _Float16* h1     = (_Float16*)xh;

    hipMemsetAsync(stats, 0, 256 * 4, stream);

    k_bhist<<<NCHUNK, 256, 0, stream>>>(edst, H, E, nbkt, chunkSz);
    k_btot<<<nbkt, 256, 0, stream>>>(H, T, NCHUNK, nbkt);
    k_bscan<<<1, 1024, 0, stream>>>(T, base, nbkt);
    k_boff<<<nbkt, NCHUNK, 0, stream>>>(H, base, NCHUNK, nbkt);
    k_bscatter<<<NCHUNK, 256, 0, stream>>>(esrc, edst, H, sorted, E, nbkt, chunkSz);
    k_bsort2<<<nbkt, 256, 0, stream>>>(sorted, base, csr, offs, N, nbkt, E);
    k_tofp16<<<2048, 256, 0, stream>>>(x, xh, N * CH / 8);
    k_aggregate_h2<<<4096, 256, 0, stream>>>((const uint2*)xh, csr, offs,
                                             (uint2*)h16, N);
    // GEMM1: h16 @ W1 + b1 -> h1 (fp16, pre-BN) + channel stats
    k_mgemm<<<512, 256, 0, stream>>>(h16, W1, b1, h1, nullptr, stats, nullptr, N, 1);
    k_bnfin<<<1, 128, 0, stream>>>(stats, gamma, beta, scsh, 1.0f / (float)N);
    // GEMM2: relu(BN(h1)) @ W2 + b2 -> relu -> fp32 out
    k_mgemm<<<512, 256, 0, stream>>>(h1, W2, b2, nullptr, (float*)d_out, nullptr, scsh, N, 0);
}